// Round 8
// baseline (3721.315 us; speedup 1.0000x reference)
//
#include <hip/hip_runtime.h>

constexpr int kDepth = 6;
constexpr int kB = 8;
constexpr int kN = 1024;
constexpr int kDim = 768;
constexpr int kH = 12;
constexpr int kDh = 64;
constexpr int kMlp = 3072;
constexpr int kRows = kB * kN;   // 8192
constexpr int kQKV = 2304;       // q(768) k(768) v(768)

typedef __attribute__((ext_vector_type(4))) float f32x4;
typedef __attribute__((ext_vector_type(8))) short bf16x8;

__device__ __forceinline__ f32x4 mfma16x16x32(bf16x8 a, bf16x8 b, f32x4 c) {
  return __builtin_amdgcn_mfma_f32_16x16x32_bf16(a, b, c, 0, 0, 0);
}

__device__ __forceinline__ unsigned short f2bf(float f) {
  unsigned int u = __builtin_bit_cast(unsigned int, f);
  u = u + 0x7FFFu + ((u >> 16) & 1u);
  return (unsigned short)(u >> 16);
}

__device__ __forceinline__ float bf2f(unsigned short u) {
  return __builtin_bit_cast(float, (unsigned int)u << 16);
}

__device__ __forceinline__ void gload_lds16(const void* g, void* l) {
  __builtin_amdgcn_global_load_lds((__attribute__((address_space(1))) void*)g,
                                   (__attribute__((address_space(3))) void*)l,
                                   16, 0, 0);
}

// ---------------- LayerNorm: f32 in -> bf16 out ----------------
__global__ __launch_bounds__(256) void ln_kernel(const float* __restrict__ x,
                                                 const float* __restrict__ gamma,
                                                 const float* __restrict__ beta,
                                                 unsigned short* __restrict__ out) {
  int row = blockIdx.x, tid = threadIdx.x;
  const float* xr = x + (size_t)row * kDim;
  float v0 = xr[tid], v1 = xr[tid + 256], v2 = xr[tid + 512];
  float s = v0 + v1 + v2;
  float q = v0 * v0 + v1 * v1 + v2 * v2;
#pragma unroll
  for (int o = 32; o >= 1; o >>= 1) {
    s += __shfl_xor(s, o);
    q += __shfl_xor(q, o);
  }
  __shared__ float ss[4], sq[4];
  int wid = tid >> 6, lane = tid & 63;
  if (lane == 0) { ss[wid] = s; sq[wid] = q; }
  __syncthreads();
  s = ss[0] + ss[1] + ss[2] + ss[3];
  q = sq[0] + sq[1] + sq[2] + sq[3];
  float mean = s * (1.0f / kDim);
  float var = q * (1.0f / kDim) - mean * mean;
  float rstd = rsqrtf(var + 1e-5f);
  unsigned short* orow = out + (size_t)row * kDim;
  orow[tid]       = f2bf((v0 - mean) * rstd * gamma[tid]       + beta[tid]);
  orow[tid + 256] = f2bf((v1 - mean) * rstd * gamma[tid + 256] + beta[tid + 256]);
  orow[tid + 512] = f2bf((v2 - mean) * rstd * gamma[tid + 512] + beta[tid + 512]);
}

// ---------------- Batched weight transpose: all 5 matrices of one layer ----------------
__global__ __launch_bounds__(256) void transpose_all(const float* __restrict__ Wq,
                                                     const float* __restrict__ Wkv,
                                                     const float* __restrict__ Wo,
                                                     const float* __restrict__ W1,
                                                     const float* __restrict__ W2,
                                                     unsigned short* __restrict__ wqkvT,
                                                     unsigned short* __restrict__ woT,
                                                     unsigned short* __restrict__ w1T,
                                                     unsigned short* __restrict__ w2T,
                                                     int L) {
  int t = blockIdx.x;
  const float* src;
  unsigned short* dst;
  int R, C, dstOff;
  if (t < 576)       { src = Wq  + (size_t)L * 768 * 768;  R = 768;  C = 768;  dst = wqkvT; dstOff = 0;   }
  else if (t < 1728) { src = Wkv + (size_t)L * 768 * 1536; R = 768;  C = 1536; dst = wqkvT; dstOff = 768; t -= 576; }
  else if (t < 2304) { src = Wo  + (size_t)L * 768 * 768;  R = 768;  C = 768;  dst = woT;   dstOff = 0;   t -= 1728; }
  else if (t < 4608) { src = W1  + (size_t)L * 768 * 3072; R = 768;  C = 3072; dst = w1T;   dstOff = 0;   t -= 2304; }
  else               { src = W2  + (size_t)L * 3072 * 768; R = 3072; C = 768;  dst = w2T;   dstOff = 0;   t -= 4608; }
  int Ct = C >> 5;
  int bx = t % Ct, by = t / Ct;
  __shared__ float tt[32][33];
  int tx = threadIdx.x & 31, ty = threadIdx.x >> 5;  // ty 0..7
  int c0 = bx * 32, r0 = by * 32;
#pragma unroll
  for (int k = 0; k < 4; ++k) {
    int r = r0 + ty + k * 8;
    tt[ty + k * 8][tx] = src[(size_t)r * C + c0 + tx];
  }
  __syncthreads();
#pragma unroll
  for (int k = 0; k < 4; ++k) {
    int c = c0 + ty + k * 8;
    dst[(size_t)(dstOff + c) * R + r0 + tx] = f2bf(tt[tx][ty + k * 8]);
  }
}

// ---------------- V transpose: qkv[b,j,1536+g*64+d] -> vT[(b*12+g)*64+d][j] ----------------
__global__ __launch_bounds__(256) void transpose_v_kernel(const unsigned short* __restrict__ qkv,
                                                          unsigned short* __restrict__ vT) {
  __shared__ unsigned short t[32][33];
  int tx = threadIdx.x & 31, ty = threadIdx.x >> 5;
  int j0 = blockIdx.x * 32, d0 = blockIdx.y * 32;
  int bg = blockIdx.z;
  int b = bg / kH, g = bg % kH;
#pragma unroll
  for (int k = 0; k < 4; ++k) {
    int j = j0 + ty + k * 8;
    t[ty + k * 8][tx] = qkv[(size_t)(b * kN + j) * kQKV + 1536 + g * 64 + d0 + tx];
  }
  __syncthreads();
#pragma unroll
  for (int k = 0; k < 4; ++k) {
    int d = d0 + ty + k * 8;
    vT[((size_t)(b * kH + g) * kDh + d) * kN + j0 + tx] = t[tx][ty + k * 8];
  }
}

// ---------------- GEMM: A[M,K]bf16 x Bt[N,K]bf16 -> epilogue ----------------
// EPI 0: C=bf16 plain; EPI 1: bf16 gelu(acc+bias); EPI 2: resid = (acc+bias)*scl + resid (f32)
template <int EPI>
__global__ __launch_bounds__(256) void gemm_kernel(const unsigned short* __restrict__ A,
                                                   const unsigned short* __restrict__ Bt,
                                                   const float* __restrict__ bias,
                                                   const float* __restrict__ scl,
                                                   float* __restrict__ resid,
                                                   unsigned short* __restrict__ C,
                                                   int K, int ldc) {
  __shared__ __align__(16) unsigned short lA[128 * 64];
  __shared__ __align__(16) unsigned short lB[128 * 64];
  int tid = threadIdx.x, wid = tid >> 6, lane = tid & 63;
  // XCD-aware bijective chunked swizzle (all grids have nwg % 8 == 0)
  int gx = gridDim.x;
  int nwg = gx * gridDim.y;
  int orig = blockIdx.y * gx + blockIdx.x;
  int chunk = nwg >> 3;
  int wg = (orig & 7) * chunk + (orig >> 3);
  int bx = wg % gx, by = wg / gx;
  int row0 = by * 128, col0 = bx * 128;
  int wr = wid >> 1, wc = wid & 1;
  f32x4 zero = {0.f, 0.f, 0.f, 0.f};
  f32x4 acc[4][4];
#pragma unroll
  for (int m = 0; m < 4; ++m)
#pragma unroll
    for (int n = 0; n < 4; ++n) acc[m][n] = zero;

  for (int kt = 0; kt < K; kt += 64) {
    __syncthreads();
#pragma unroll
    for (int t = 0; t < 4; ++t) {
      int cbase = wid * 256 + t * 64;
      int c = cbase + lane;
      int r = c >> 3, slot = c & 7;
      int k8 = slot ^ (r & 7);  // source-swizzle so LDS holds XOR-swizzled layout
      gload_lds16(&A[(size_t)(row0 + r) * K + kt + k8 * 8], &lA[cbase * 8]);
      gload_lds16(&Bt[(size_t)(col0 + r) * K + kt + k8 * 8], &lB[cbase * 8]);
    }
    __syncthreads();
#pragma unroll
    for (int kk = 0; kk < 2; ++kk) {
      bf16x8 af[4], bfr[4];
      int kslot = kk * 4 + (lane >> 4);
#pragma unroll
      for (int m = 0; m < 4; ++m) {
        int r = wr * 64 + m * 16 + (lane & 15);
        af[m] = *reinterpret_cast<const bf16x8*>(&lA[r * 64 + ((kslot ^ (r & 7)) << 3)]);
      }
#pragma unroll
      for (int n = 0; n < 4; ++n) {
        int r = wc * 64 + n * 16 + (lane & 15);
        bfr[n] = *reinterpret_cast<const bf16x8*>(&lB[r * 64 + ((kslot ^ (r & 7)) << 3)]);
      }
#pragma unroll
      for (int m = 0; m < 4; ++m)
#pragma unroll
        for (int n = 0; n < 4; ++n) acc[m][n] = mfma16x16x32(af[m], bfr[n], acc[m][n]);
    }
  }
#pragma unroll
  for (int m = 0; m < 4; ++m)
#pragma unroll
    for (int n = 0; n < 4; ++n)
#pragma unroll
      for (int r4 = 0; r4 < 4; ++r4) {
        int row = row0 + wr * 64 + m * 16 + ((lane >> 4) << 2) + r4;
        int col = col0 + wc * 64 + n * 16 + (lane & 15);
        float v = acc[m][n][r4];
        if (EPI == 0) {
          C[(size_t)row * ldc + col] = f2bf(v);
        } else if (EPI == 1) {
          v += bias[col];
          v = 0.5f * v * (1.f + erff(v * 0.70710678118654752f));
          C[(size_t)row * ldc + col] = f2bf(v);
        } else {
          v = (v + bias[col]) * scl[col];
          size_t idx = (size_t)row * kDim + col;
          resid[idx] = resid[idx] + v;
        }
      }
}

// ---------------- Fused talking-heads attention (two-pass, QK^T recomputed) ----------------
// Block = (b, 32-row i-tile). Pass 1: psum_g[i] = sum_j exp(clamp(premix(S)));
// Pass 2: recompute S, E = exp*lg (in-place in T), postmix -> P2 (LDS), PV -> attnout.
__global__ __launch_bounds__(256) void fused_attn_kernel(
    const unsigned short* __restrict__ qkv,
    const float* __restrict__ pre, const float* __restrict__ post,
    const unsigned short* __restrict__ vT,
    unsigned short* __restrict__ attnout) {
  constexpr int TROW = 24;    // ushorts per (i,j) slot: 16 h + 8 pad
  constexpr int P2ROW = 40;   // ushorts per P2 row (80B, breaks bank alignment)
  __shared__ __align__(16) unsigned short T[1024 * TROW];        // 48KB
  __shared__ __align__(16) unsigned short P2[12 * 32 * P2ROW];   // 30KB
  __shared__ __align__(16) unsigned short preA[16 * 32];
  __shared__ __align__(16) unsigned short postA[16 * 32];
  int tid = threadIdx.x, wid = tid >> 6, lane = tid & 63;
  int kg = lane >> 4, l15 = lane & 15;
  int it0 = blockIdx.x * 32;
  int b = blockIdx.y;

  for (int idx = tid; idx < 512; idx += 256) {
    int m = idx >> 5, k = idx & 31;
    bool in = (m < 12 && k < 12);
    preA[idx]  = f2bf(in ? pre[k * 12 + m] * 0.125f : 0.f);
    postA[idx] = f2bf(in ? post[k * 12 + m] : 0.f);
  }
  // zero h-slots 12..15 (avoid NaN garbage; kept finite by E writes thereafter)
  for (int idx = tid; idx < 2048; idx += 256) {
    int pos = idx >> 1;
    *(unsigned int*)&T[pos * TROW + 12 + (idx & 1) * 2] = 0u;
  }
  __syncthreads();
  bf16x8 preF  = *(const bf16x8*)&preA[l15 * 32 + kg * 8];   // A[g][h]
  bf16x8 postF = *(const bf16x8*)&postA[l15 * 32 + kg * 8];  // A[g2][g]
  f32x4 zero = {0.f, 0.f, 0.f, 0.f};
  bf16x8 zfrag = {0, 0, 0, 0, 0, 0, 0, 0};

  auto qkt_tile = [&](int j0) {  // scores for (32i x 32j) -> T[pos][h], h<12
#pragma unroll
    for (int rep = 0; rep < 3; ++rep) {
      int h = rep * 4 + wid;
      f32x4 acc2[2][2];
      acc2[0][0] = zero; acc2[0][1] = zero; acc2[1][0] = zero; acc2[1][1] = zero;
#pragma unroll
      for (int kk = 0; kk < 2; ++kk) {
        bf16x8 aq[2], bk[2];
#pragma unroll
        for (int m = 0; m < 2; ++m)
          aq[m] = *(const bf16x8*)&qkv[(size_t)(b * kN + it0 + m * 16 + l15) * kQKV +
                                       h * 64 + kk * 32 + kg * 8];
#pragma unroll
        for (int n = 0; n < 2; ++n)
          bk[n] = *(const bf16x8*)&qkv[(size_t)(b * kN + j0 + n * 16 + l15) * kQKV +
                                       768 + h * 64 + kk * 32 + kg * 8];
#pragma unroll
        for (int m = 0; m < 2; ++m)
#pragma unroll
          for (int n = 0; n < 2; ++n) acc2[m][n] = mfma16x16x32(aq[m], bk[n], acc2[m][n]);
      }
#pragma unroll
      for (int m = 0; m < 2; ++m)
#pragma unroll
        for (int n = 0; n < 2; ++n)
#pragma unroll
          for (int r = 0; r < 4; ++r)
            T[((m * 16 + kg * 4 + r) * 32 + n * 16 + l15) * TROW + h] = f2bf(acc2[m][n][r]);
    }
  };

  // ---- pass 1: denominators ----
  float psum[8][4];
#pragma unroll
  for (int il = 0; il < 8; ++il)
#pragma unroll
    for (int r = 0; r < 4; ++r) psum[il][r] = 0.f;

  for (int t = 0; t < 32; ++t) {
    __syncthreads();
    qkt_tile(t * 32);
    __syncthreads();
#pragma unroll
    for (int grp = 0; grp < 16; ++grp) {
      int pos = wid * 256 + grp * 16 + l15;
      bf16x8 bfrag = (kg < 2) ? *(const bf16x8*)&T[pos * TROW + kg * 8] : zfrag;
      f32x4 d = mfma16x16x32(preF, bfrag, zero);  // D[g=kg*4+r][pos=l15]
#pragma unroll
      for (int r = 0; r < 4; ++r) {
        float dc = fminf(fmaxf(d[r], -15.f), 15.f);
        float ee = (kg == 3) ? 0.f : __expf(dc);
        psum[grp >> 1][r] += ee;
      }
    }
  }
  // reduce over the 16-lane group -> lg in registers (same lane needs same (ii,g) in pass 2)
  float lgr[8][4];
#pragma unroll
  for (int il = 0; il < 8; ++il)
#pragma unroll
    for (int r = 0; r < 4; ++r) {
      float s = psum[il][r];
      s += __shfl_xor(s, 1); s += __shfl_xor(s, 2);
      s += __shfl_xor(s, 4); s += __shfl_xor(s, 8);
      lgr[il][r] = (kg < 3) ? (1.f / s) : 0.f;
    }

  // ---- pass 2: E -> postmix -> PV ----
  f32x4 pvacc[3][2][4];
#pragma unroll
  for (int gg = 0; gg < 3; ++gg)
#pragma unroll
    for (int hh = 0; hh < 2; ++hh)
#pragma unroll
      for (int n = 0; n < 4; ++n) pvacc[gg][hh][n] = zero;
  int g2w = wid * 3;

  for (int t = 0; t < 32; ++t) {
    int j0 = t * 32;
    __syncthreads();
    qkt_tile(j0);
    __syncthreads();
#pragma unroll
    for (int grp = 0; grp < 16; ++grp) {
      int pos = wid * 256 + grp * 16 + l15;
      bf16x8 bfrag = (kg < 2) ? *(const bf16x8*)&T[pos * TROW + kg * 8] : zfrag;
      f32x4 d = mfma16x16x32(preF, bfrag, zero);
      float pe[4];
#pragma unroll
      for (int r = 0; r < 4; ++r) {
        float dc = fminf(fmaxf(d[r], -15.f), 15.f);
        float ee = (kg == 3) ? 0.f : __expf(dc);
        pe[r] = ee * lgr[grp >> 1][r];
      }
      unsigned int w0, w1;
      asm("v_cvt_pk_bf16_f32 %0, %1, %2" : "=v"(w0) : "v"(pe[0]), "v"(pe[1]));
      asm("v_cvt_pk_bf16_f32 %0, %1, %2" : "=v"(w1) : "v"(pe[2]), "v"(pe[3]));
      // in-place E over T: same-wave ds_read -> MFMA -> ds_write ordering; pos disjoint per grp/wave
      *(unsigned int*)&T[pos * TROW + kg * 4] = w0;
      *(unsigned int*)&T[pos * TROW + kg * 4 + 2] = w1;
    }
    __syncthreads();
#pragma unroll
    for (int grp = 0; grp < 16; ++grp) {
      int pos = wid * 256 + grp * 16 + l15;
      bf16x8 efrag = (kg < 2) ? *(const bf16x8*)&T[pos * TROW + kg * 8] : zfrag;
      f32x4 d2 = mfma16x16x32(postF, efrag, zero);  // D[g2=kg*4+r][pos=l15]
      if (kg < 3) {
        int ii = wid * 8 + (grp >> 1);
        int jj = (grp & 1) * 16 + l15;
#pragma unroll
        for (int r = 0; r < 4; ++r)
          P2[((kg * 4 + r) * 32 + ii) * P2ROW + jj] = f2bf(d2[r]);
      }
    }
    __syncthreads();
    // PV: each wave owns 3 g2 heads
#pragma unroll
    for (int gg = 0; gg < 3; ++gg) {
      int g2 = g2w + gg;
      bf16x8 ap[2];
#pragma unroll
      for (int hh = 0; hh < 2; ++hh)
        ap[hh] = *(const bf16x8*)&P2[((size_t)g2 * 32 + hh * 16 + l15) * P2ROW + kg * 8];
#pragma unroll
      for (int n = 0; n < 4; ++n) {
        bf16x8 bv = *(const bf16x8*)&vT[((size_t)(b * 12 + g2) * 64 + n * 16 + l15) * kN +
                                        j0 + kg * 8];
#pragma unroll
        for (int hh = 0; hh < 2; ++hh)
          pvacc[gg][hh][n] = mfma16x16x32(ap[hh], bv, pvacc[gg][hh][n]);
      }
    }
  }
#pragma unroll
  for (int gg = 0; gg < 3; ++gg)
#pragma unroll
    for (int hh = 0; hh < 2; ++hh)
#pragma unroll
      for (int n = 0; n < 4; ++n)
#pragma unroll
        for (int r = 0; r < 4; ++r) {
          int tok = it0 + hh * 16 + kg * 4 + r;
          int col = (g2w + gg) * 64 + n * 16 + l15;
          attnout[(size_t)(b * kN + tok) * kDim + col] = f2bf(pvacc[gg][hh][n][r]);
        }
}

extern "C" void kernel_launch(void* const* d_in, const int* in_sizes, int n_in,
                              void* d_out, int out_size, void* d_ws, size_t ws_size,
                              hipStream_t stream) {
  (void)in_sizes; (void)n_in; (void)out_size; (void)ws_size;
  const float* x     = (const float*)d_in[0];
  const float* ln1_g = (const float*)d_in[1];
  const float* ln1_b = (const float*)d_in[2];
  const float* Wq    = (const float*)d_in[3];
  const float* Wkv   = (const float*)d_in[4];
  const float* pre   = (const float*)d_in[5];
  const float* post  = (const float*)d_in[6];
  const float* Wo    = (const float*)d_in[7];
  const float* bo    = (const float*)d_in[8];
  const float* s1    = (const float*)d_in[9];
  const float* ln2_g = (const float*)d_in[10];
  const float* ln2_b = (const float*)d_in[11];
  const float* W1    = (const float*)d_in[12];
  const float* b1    = (const float*)d_in[13];
  const float* W2    = (const float*)d_in[14];
  const float* b2    = (const float*)d_in[15];
  const float* s2    = (const float*)d_in[16];
  float* xo = (float*)d_out;

  char* ws = (char*)d_ws;
  size_t off = 0;
  auto alloc = [&](size_t bytes) -> void* {
    void* p = ws + off;
    off += (bytes + 255) & ~(size_t)255;
    return p;
  };
  unsigned short* h_buf   = (unsigned short*)alloc((size_t)kRows * kDim * 2);
  unsigned short* qkv     = (unsigned short*)alloc((size_t)kRows * kQKV * 2);
  unsigned short* vT      = (unsigned short*)alloc((size_t)kB * kH * kDh * kN * 2);
  unsigned short* attnout = (unsigned short*)alloc((size_t)kRows * kDim * 2);
  unsigned short* mid     = (unsigned short*)alloc((size_t)kRows * kMlp * 2);
  unsigned short* wqkvT   = (unsigned short*)alloc((size_t)kQKV * kDim * 2);
  unsigned short* woT     = (unsigned short*)alloc((size_t)kDim * kDim * 2);
  unsigned short* w1T     = (unsigned short*)alloc((size_t)kMlp * kDim * 2);
  unsigned short* w2T     = (unsigned short*)alloc((size_t)kDim * kMlp * 2);

  hipMemcpyAsync(xo, x, (size_t)kRows * kDim * 4, hipMemcpyDeviceToDevice, stream);

  for (int L = 0; L < kDepth; ++L) {
    // --- attention block ---
    ln_kernel<<<kRows, 256, 0, stream>>>(xo, ln1_g + L * kDim, ln1_b + L * kDim, h_buf);
    transpose_all<<<6912, 256, 0, stream>>>(Wq, Wkv, Wo, W1, W2, wqkvT, woT, w1T, w2T, L);

    gemm_kernel<0><<<dim3(kQKV / 128, kRows / 128), 256, 0, stream>>>(
        h_buf, wqkvT, nullptr, nullptr, nullptr, qkv, kDim, kQKV);
    transpose_v_kernel<<<dim3(kN / 32, kDh / 32, kB * kH), 256, 0, stream>>>(qkv, vT);

    fused_attn_kernel<<<dim3(kN / 32, kB), 256, 0, stream>>>(
        qkv, pre + L * 144, post + L * 144, vT, attnout);

    gemm_kernel<2><<<dim3(kDim / 128, kRows / 128), 256, 0, stream>>>(
        attnout, woT, bo + L * kDim, s1 + L * kDim, xo, nullptr, kDim, kDim);

    // --- MLP block ---
    ln_kernel<<<kRows, 256, 0, stream>>>(xo, ln2_g + L * kDim, ln2_b + L * kDim, h_buf);
    gemm_kernel<1><<<dim3(kMlp / 128, kRows / 128), 256, 0, stream>>>(
        h_buf, w1T, b1 + L * kMlp, nullptr, nullptr, mid, kDim, kMlp);
    gemm_kernel<2><<<dim3(kDim / 128, kRows / 128), 256, 0, stream>>>(
        mid, w2T, b2 + L * kDim, s2 + L * kDim, xo, nullptr, kMlp, kDim);
  }
}